// Round 1
// baseline (120.401 us; speedup 1.0000x reference)
//
#include <hip/hip_runtime.h>
#include <hip/hip_bf16.h>

// VectorP1FunctionSpace: out[b,n,0] = sum_v min_k(relu(x . W[v,k] + c[v,k])) * wx[v]
//                        out[b,n,1] = same with wy.
// B*N = 16384 points, V = 1089 vertices, K = 6 cells/vertex (padded, c=1e9).
// Compute-bound on fp32 VALU. Strategy: 1 thread per point, vertex dim split
// into VSPLIT segments across blockIdx.y for occupancy; fp32 atomicAdd combine.

#define VSPLIT 8
#define BLOCK 256

template <int K>
__global__ __launch_bounds__(BLOCK) void p1_eval_kernel(
    const float* __restrict__ x,   // [BN, 2]
    const float* __restrict__ W,   // [V, K, 2]
    const float* __restrict__ c,   // [V, K]
    const float* __restrict__ wx,  // [V]
    const float* __restrict__ wy,  // [V]
    float* __restrict__ out,       // [BN, 2]
    int BN, int V) {
  int pt = blockIdx.x * BLOCK + threadIdx.x;
  if (pt >= BN) return;
  float x0 = x[2 * pt];
  float x1 = x[2 * pt + 1];

  int seg = blockIdx.y;
  int v0 = (int)(((long long)V * seg) / VSPLIT);
  int v1 = (int)(((long long)V * (seg + 1)) / VSPLIT);

  float sx = 0.f, sy = 0.f;
  for (int v = v0; v < v1; ++v) {
    float m = 1e30f;
#pragma unroll
    for (int k = 0; k < K; ++k) {
      // All of W/c are wave-uniform addresses -> scalar loads.
      float w0 = W[((v * K) + k) * 2 + 0];
      float w1 = W[((v * K) + k) * 2 + 1];
      float cc = c[v * K + k];
      float t = fmaf(x0, w0, fmaf(x1, w1, cc));
      t = fmaxf(t, 0.f);
      m = fminf(m, t);
    }
    sx = fmaf(m, wx[v], sx);
    sy = fmaf(m, wy[v], sy);
  }
  atomicAdd(&out[2 * pt + 0], sx);
  atomicAdd(&out[2 * pt + 1], sy);
}

// Generic runtime-K fallback (same structure, un-unrolled inner loop).
__global__ __launch_bounds__(BLOCK) void p1_eval_kernel_gen(
    const float* __restrict__ x, const float* __restrict__ W,
    const float* __restrict__ c, const float* __restrict__ wx,
    const float* __restrict__ wy, float* __restrict__ out,
    int BN, int V, int K) {
  int pt = blockIdx.x * BLOCK + threadIdx.x;
  if (pt >= BN) return;
  float x0 = x[2 * pt];
  float x1 = x[2 * pt + 1];
  int seg = blockIdx.y;
  int v0 = (int)(((long long)V * seg) / VSPLIT);
  int v1 = (int)(((long long)V * (seg + 1)) / VSPLIT);
  float sx = 0.f, sy = 0.f;
  for (int v = v0; v < v1; ++v) {
    float m = 1e30f;
    for (int k = 0; k < K; ++k) {
      float w0 = W[((v * K) + k) * 2 + 0];
      float w1 = W[((v * K) + k) * 2 + 1];
      float cc = c[v * K + k];
      float t = fmaf(x0, w0, fmaf(x1, w1, cc));
      t = fmaxf(t, 0.f);
      m = fminf(m, t);
    }
    sx = fmaf(m, wx[v], sx);
    sy = fmaf(m, wy[v], sy);
  }
  atomicAdd(&out[2 * pt + 0], sx);
  atomicAdd(&out[2 * pt + 1], sy);
}

extern "C" void kernel_launch(void* const* d_in, const int* in_sizes, int n_in,
                              void* d_out, int out_size, void* d_ws, size_t ws_size,
                              hipStream_t stream) {
  const float* x  = (const float*)d_in[0];   // [B, N, 2]
  const float* W  = (const float*)d_in[1];   // [V, K, 2]
  const float* c  = (const float*)d_in[2];   // [V, K]
  const float* wx = (const float*)d_in[3];   // [V]
  const float* wy = (const float*)d_in[4];   // [V]
  float* out = (float*)d_out;                // [B, N, 2]

  int BN = in_sizes[0] / 2;
  int V  = in_sizes[3];
  int K  = in_sizes[2] / V;

  // d_out is poisoned 0xAA before every launch; atomics need zeros.
  hipMemsetAsync(d_out, 0, (size_t)out_size * sizeof(float), stream);

  dim3 grid((BN + BLOCK - 1) / BLOCK, VSPLIT);
  if (K == 6) {
    p1_eval_kernel<6><<<grid, BLOCK, 0, stream>>>(x, W, c, wx, wy, out, BN, V);
  } else {
    p1_eval_kernel_gen<<<grid, BLOCK, 0, stream>>>(x, W, c, wx, wy, out, BN, V, K);
  }
}

// Round 2
// 102.354 us; speedup vs baseline: 1.1763x; 1.1763x over previous
//
#include <hip/hip_runtime.h>
#include <hip/hip_bf16.h>

// VectorP1FunctionSpace: out[pt,0] = sum_v min_k(relu(x . W[v,k] + c[v,k])) * wx[v]
//                        out[pt,1] = same with wy.
// BN = 16384 points, V = 1089 vertices, K = 6 (padded with c=1e9).
// Compute-bound fp32 VALU (no fp32 MFMA on CDNA4). R1 showed VALUBusy=17%:
// latency-bound on the serial fmin chain + scalar-load waits.
// R2: 4 points/thread (ILP-4), tree-min (depth 3), VSPLIT=32 for full-chip TLP.

#define VSPLIT 32
#define BLOCK 256
#define PTS 4

template <int K>
__global__ __launch_bounds__(BLOCK) void p1_eval_kernel(
    const float* __restrict__ x,   // [BN, 2]
    const float* __restrict__ W,   // [V, K, 2]
    const float* __restrict__ c,   // [V, K]
    const float* __restrict__ wx,  // [V]
    const float* __restrict__ wy,  // [V]
    float* __restrict__ out,       // [BN, 2]
    int BN, int V) {
  int tid = blockIdx.x * BLOCK + threadIdx.x;
  int pbase = tid * PTS;
  if (pbase >= BN) return;

  // Load 4 points' coords: 8 floats = 2 x float4 (32B-aligned).
  float px[PTS], py[PTS];
  {
    const float4* xv = (const float4*)(x + 2 * pbase);
    float4 a = xv[0], b = xv[1];
    px[0] = a.x; py[0] = a.y; px[1] = a.z; py[1] = a.w;
    px[2] = b.x; py[2] = b.y; px[3] = b.z; py[3] = b.w;
  }

  int seg = blockIdx.y;
  int v0 = (int)(((long long)V * seg) / VSPLIT);
  int v1 = (int)(((long long)V * (seg + 1)) / VSPLIT);

  float sx[PTS], sy[PTS];
#pragma unroll
  for (int p = 0; p < PTS; ++p) { sx[p] = 0.f; sy[p] = 0.f; }

  for (int v = v0; v < v1; ++v) {
    // Wave-uniform addresses -> scalar loads (free of VALU cost).
    float w0[K], w1[K], cc[K];
#pragma unroll
    for (int k = 0; k < K; ++k) {
      w0[k] = W[((v * K) + k) * 2 + 0];
      w1[k] = W[((v * K) + k) * 2 + 1];
      cc[k] = c[v * K + k];
    }
    float vx = wx[v], vy = wy[v];
#pragma unroll
    for (int p = 0; p < PTS; ++p) {
      float t[K];
#pragma unroll
      for (int k = 0; k < K; ++k) {
        t[k] = fmaxf(fmaf(px[p], w0[k], fmaf(py[p], w1[k], cc[k])), 0.f);
      }
      // Tree min: depth 3 instead of serial depth 5 (K=6).
      float m01 = fminf(t[0], t[1]);
      float m23 = fminf(t[2], t[3]);
      float m45 = fminf(t[4], t[5]);
      float m = fminf(fminf(m01, m23), m45);
      sx[p] = fmaf(m, vx, sx[p]);
      sy[p] = fmaf(m, vy, sy[p]);
    }
  }
#pragma unroll
  for (int p = 0; p < PTS; ++p) {
    int pt = pbase + p;
    if (pt < BN) {
      atomicAdd(&out[2 * pt + 0], sx[p]);
      atomicAdd(&out[2 * pt + 1], sy[p]);
    }
  }
}

// Generic runtime-K fallback (1 pt/thread, un-unrolled).
__global__ __launch_bounds__(BLOCK) void p1_eval_kernel_gen(
    const float* __restrict__ x, const float* __restrict__ W,
    const float* __restrict__ c, const float* __restrict__ wx,
    const float* __restrict__ wy, float* __restrict__ out,
    int BN, int V, int K) {
  int pt = blockIdx.x * BLOCK + threadIdx.x;
  if (pt >= BN) return;
  float x0 = x[2 * pt];
  float x1 = x[2 * pt + 1];
  int seg = blockIdx.y;
  int v0 = (int)(((long long)V * seg) / VSPLIT);
  int v1 = (int)(((long long)V * (seg + 1)) / VSPLIT);
  float sx = 0.f, sy = 0.f;
  for (int v = v0; v < v1; ++v) {
    float m = 1e30f;
    for (int k = 0; k < K; ++k) {
      float w0 = W[((v * K) + k) * 2 + 0];
      float w1 = W[((v * K) + k) * 2 + 1];
      float cc = c[v * K + k];
      float t = fmaf(x0, w0, fmaf(x1, w1, cc));
      t = fmaxf(t, 0.f);
      m = fminf(m, t);
    }
    sx = fmaf(m, wx[v], sx);
    sy = fmaf(m, wy[v], sy);
  }
  atomicAdd(&out[2 * pt + 0], sx);
  atomicAdd(&out[2 * pt + 1], sy);
}

extern "C" void kernel_launch(void* const* d_in, const int* in_sizes, int n_in,
                              void* d_out, int out_size, void* d_ws, size_t ws_size,
                              hipStream_t stream) {
  const float* x  = (const float*)d_in[0];   // [B, N, 2]
  const float* W  = (const float*)d_in[1];   // [V, K, 2]
  const float* c  = (const float*)d_in[2];   // [V, K]
  const float* wx = (const float*)d_in[3];   // [V]
  const float* wy = (const float*)d_in[4];   // [V]
  float* out = (float*)d_out;                // [BN, 2]

  int BN = in_sizes[0] / 2;
  int V  = in_sizes[3];
  int K  = in_sizes[2] / V;

  // d_out is poisoned 0xAA before every launch; atomics need zeros.
  hipMemsetAsync(d_out, 0, (size_t)out_size * sizeof(float), stream);

  if (K == 6 && (BN % PTS) == 0) {
    int nthreads = BN / PTS;
    dim3 grid((nthreads + BLOCK - 1) / BLOCK, VSPLIT);
    p1_eval_kernel<6><<<grid, BLOCK, 0, stream>>>(x, W, c, wx, wy, out, BN, V);
  } else {
    dim3 grid((BN + BLOCK - 1) / BLOCK, VSPLIT);
    p1_eval_kernel_gen<<<grid, BLOCK, 0, stream>>>(x, W, c, wx, wy, out, BN, V, K);
  }
}

// Round 3
// 82.951 us; speedup vs baseline: 1.4515x; 1.2339x over previous
//
#include <hip/hip_runtime.h>
#include <hip/hip_bf16.h>

// VectorP1FunctionSpace: out[pt,0] = sum_v min_k(relu(x . W[v,k] + c[v,k])) * wx[v]
//                        out[pt,1] = same with wy.
// BN = 16384 points, V = 1089 vertices, K = 6 (padded with c=1e9).
// fp32 VALU compute (no fp32 MFMA). R2 post-mortem: VALUBusy 21%, occupancy
// 15%, 32 MB HBM write-through from atomics -> latency-bound with too few
// waves. R3: two-phase reduction via d_ws (plain coalesced stores, no
// atomics), VSPLIT=64 -> 1024 blocks = 16 waves/CU, PTS=4 ILP kept.

#define BLOCK 256
#define PTS 4
#define VSPLIT_MAX 64

template <int K>
__global__ __launch_bounds__(BLOCK) void p1_phase1(
    const float* __restrict__ x,   // [BN, 2]
    const float* __restrict__ W,   // [V, K, 2]
    const float* __restrict__ c,   // [V, K]
    const float* __restrict__ wx,  // [V]
    const float* __restrict__ wy,  // [V]
    float* __restrict__ partial,   // [vsplit, BN, 2]
    int BN, int V, int vsplit) {
  int tid = blockIdx.x * BLOCK + threadIdx.x;
  int pbase = tid * PTS;
  if (pbase >= BN) return;

  // 4 points' coords: 8 floats = 2 x float4, coalesced & 32B-aligned.
  const float4* xv = (const float4*)(x + 2 * pbase);
  float4 a = xv[0], b = xv[1];
  float px[PTS] = {a.x, a.z, b.x, b.z};
  float py[PTS] = {a.y, a.w, b.y, b.w};

  int seg = blockIdx.y;
  int v0 = (int)(((long long)V * seg) / vsplit);
  int v1 = (int)(((long long)V * (seg + 1)) / vsplit);

  float sx[PTS] = {0.f, 0.f, 0.f, 0.f};
  float sy[PTS] = {0.f, 0.f, 0.f, 0.f};

#pragma unroll 2
  for (int v = v0; v < v1; ++v) {
    // Wave-uniform addresses -> s_load (scalar pipe, no VALU slots).
    float w0[K], w1[K], cc[K];
#pragma unroll
    for (int k = 0; k < K; ++k) {
      w0[k] = W[((v * K) + k) * 2 + 0];
      w1[k] = W[((v * K) + k) * 2 + 1];
      cc[k] = c[v * K + k];
    }
    float vx = wx[v], vy = wy[v];
#pragma unroll
    for (int p = 0; p < PTS; ++p) {
      float t[K];
#pragma unroll
      for (int k = 0; k < K; ++k) {
        t[k] = fmaxf(fmaf(px[p], w0[k], fmaf(py[p], w1[k], cc[k])), 0.f);
      }
      float m01 = fminf(t[0], t[1]);
      float m23 = fminf(t[2], t[3]);
      float m45 = fminf(t[4], t[5]);
      float m = fminf(fminf(m01, m23), m45);
      sx[p] = fmaf(m, vx, sx[p]);
      sy[p] = fmaf(m, vy, sy[p]);
    }
  }

  // Coalesced float4 stores of the interleaved (sx, sy) partials.
  float4* o = (float4*)(partial + (size_t)seg * BN * 2 + 2 * pbase);
  o[0] = make_float4(sx[0], sy[0], sx[1], sy[1]);
  o[1] = make_float4(sx[2], sy[2], sx[3], sy[3]);
}

__global__ __launch_bounds__(BLOCK) void p1_phase2(
    const float* __restrict__ partial,  // [vsplit, BN2]
    float* __restrict__ out,            // [BN2]
    int BN2, int vsplit) {
  int i = blockIdx.x * BLOCK + threadIdx.x;
  if (i >= BN2) return;
  float s0 = 0.f, s1 = 0.f, s2 = 0.f, s3 = 0.f;
  int s = 0;
  for (; s + 4 <= vsplit; s += 4) {
    s0 += partial[(size_t)(s + 0) * BN2 + i];
    s1 += partial[(size_t)(s + 1) * BN2 + i];
    s2 += partial[(size_t)(s + 2) * BN2 + i];
    s3 += partial[(size_t)(s + 3) * BN2 + i];
  }
  for (; s < vsplit; ++s) s0 += partial[(size_t)s * BN2 + i];
  out[i] = (s0 + s1) + (s2 + s3);
}

// Fallback: atomic single-kernel version (generic K, 1 pt/thread).
#define FB_VSPLIT 32
__global__ __launch_bounds__(BLOCK) void p1_eval_kernel_gen(
    const float* __restrict__ x, const float* __restrict__ W,
    const float* __restrict__ c, const float* __restrict__ wx,
    const float* __restrict__ wy, float* __restrict__ out,
    int BN, int V, int K) {
  int pt = blockIdx.x * BLOCK + threadIdx.x;
  if (pt >= BN) return;
  float x0 = x[2 * pt];
  float x1 = x[2 * pt + 1];
  int seg = blockIdx.y;
  int v0 = (int)(((long long)V * seg) / FB_VSPLIT);
  int v1 = (int)(((long long)V * (seg + 1)) / FB_VSPLIT);
  float sx = 0.f, sy = 0.f;
  for (int v = v0; v < v1; ++v) {
    float m = 1e30f;
    for (int k = 0; k < K; ++k) {
      float w0 = W[((v * K) + k) * 2 + 0];
      float w1 = W[((v * K) + k) * 2 + 1];
      float cc = c[v * K + k];
      float t = fmaf(x0, w0, fmaf(x1, w1, cc));
      t = fmaxf(t, 0.f);
      m = fminf(m, t);
    }
    sx = fmaf(m, wx[v], sx);
    sy = fmaf(m, wy[v], sy);
  }
  atomicAdd(&out[2 * pt + 0], sx);
  atomicAdd(&out[2 * pt + 1], sy);
}

extern "C" void kernel_launch(void* const* d_in, const int* in_sizes, int n_in,
                              void* d_out, int out_size, void* d_ws, size_t ws_size,
                              hipStream_t stream) {
  const float* x  = (const float*)d_in[0];   // [B, N, 2]
  const float* W  = (const float*)d_in[1];   // [V, K, 2]
  const float* c  = (const float*)d_in[2];   // [V, K]
  const float* wx = (const float*)d_in[3];   // [V]
  const float* wy = (const float*)d_in[4];   // [V]
  float* out = (float*)d_out;                // [BN, 2]

  int BN = in_sizes[0] / 2;
  int V  = in_sizes[3];
  int K  = in_sizes[2] / V;
  int BN2 = BN * 2;

  // Fit vsplit into the workspace: need vsplit * BN2 * 4 bytes.
  int vsplit = VSPLIT_MAX;
  size_t per_seg = (size_t)BN2 * sizeof(float);
  if ((size_t)vsplit * per_seg > ws_size) {
    vsplit = (int)(ws_size / per_seg);
  }

  if (K == 6 && (BN % (PTS * 4)) == 0 && vsplit >= 4) {
    float* partial = (float*)d_ws;
    int nthreads = BN / PTS;
    dim3 g1((nthreads + BLOCK - 1) / BLOCK, vsplit);
    p1_phase1<6><<<g1, BLOCK, 0, stream>>>(x, W, c, wx, wy, partial, BN, V, vsplit);
    dim3 g2((BN2 + BLOCK - 1) / BLOCK);
    p1_phase2<<<g2, BLOCK, 0, stream>>>(partial, out, BN2, vsplit);
  } else {
    hipMemsetAsync(d_out, 0, (size_t)out_size * sizeof(float), stream);
    dim3 grid((BN + BLOCK - 1) / BLOCK, FB_VSPLIT);
    p1_eval_kernel_gen<<<grid, BLOCK, 0, stream>>>(x, W, c, wx, wy, out, BN, V, K);
  }
}